// Round 5
// baseline (97.860 us; speedup 1.0000x reference)
//
#include <hip/hip_runtime.h>
#include <stdint.h>

// ScoreAggregation: N=8192, T=4 x E=131072 edges, H=4 heads.
// out_i = mean_h [ (S_total + sum_nz (e^leaky(A_ij)-1) s_j) / (N + sum_nz (e^leaky(A_ij)-1)) ]
// A_ij[h] = c_tot*(s_i*w_src[h] + s_j*w_tgt[h]) + sum_t cnt_t*emb[h][t]
// Dedup at (i,j) required (nonlinearity after aggregation).
// r4 lesson: both kernels ~90% latency stall. -> max occupancy: 256 scatter
// blocks (full GPU), 2048 aggregate blocks (8/CU, 32 waves/CU), tiny LDS.

#define NN 8192
#define TT 4
#define EE 131072
#define DD 32
#define HH 4
#define NEG_SLOPE 0.2f

#define NB    2048       // buckets = src>>2
#define RPB   4          // rows per bucket
#define SEG   128        // LDS hash slots per row (max distinct/row ~100)
#define ABLK  256        // kA scatter blocks
#define CAPBB 12         // capacity per (bucket, kA-block) sub-run; mean 1
#define A_EPT 8          // edges/thread: 256 blk x 256 thr x 8 = 524288
#define EMPTY 0xFFFFFFFFu

// ws layout:
//   cnt : u8 [NB*ABLK]          @ 0        (512 KB)
//   f   : float[25]             @ 524288   (pad to +1024)
//   buf : u32[NB*ABLK*CAPBB]    @ 525312   (~25 MB)
// f: f[0]=S_total, f[1..4]=w_src, f[5..8]=w_tgt, f[9+h*4+t]=emb

__global__ void __launch_bounds__(256) kA(const int* __restrict__ ei,
                                          const float* __restrict__ scores,
                                          const float* __restrict__ ete,
                                          const float* __restrict__ aw,
                                          uint8_t* __restrict__ cnt,
                                          uint32_t* __restrict__ buf,
                                          float* __restrict__ f) {
    int tid = threadIdx.x;
    if (blockIdx.x == ABLK) {            // consts block
        __shared__ float red[256];
        float s = 0.f;
        for (int i = tid; i < NN; i += 256) s += scores[i];
        red[tid] = s;
        __syncthreads();
        for (int off = 128; off > 0; off >>= 1) {
            if (tid < off) red[tid] += red[tid + off];
            __syncthreads();
        }
        if (tid == 0) f[0] = red[0];
        if (tid < HH) {
            f[1 + tid] = aw[tid * (DD + 2)];            // w[0]
            f[5 + tid] = aw[tid * (DD + 2) + DD + 1];   // w[D+1]
        }
        if (tid < HH * TT) {
            int h = tid / TT, t = tid % TT;
            float acc = 0.f;
            for (int d = 0; d < DD; ++d)
                acc += ete[t * DD + d] * aw[h * (DD + 2) + 1 + d];
            f[9 + tid] = acc;
        }
        return;
    }

    __shared__ uint32_t hist[NB];        // 8 KB
    for (int i = tid; i < NB; i += 256) hist[i] = 0;
    __syncthreads();

    uint32_t gtid = blockIdx.x * 256u + (uint32_t)tid;   // [0, 65536)
    uint32_t t  = gtid >> 14;                            // 16384 threads/type
    uint32_t e0 = (gtid & 16383u) * A_EPT;
    const int4* sp = (const int4*)(ei + (size_t)(t * 2) * EE + e0);
    const int4* tp = (const int4*)(ei + (size_t)(t * 2 + 1) * EE + e0);

    uint32_t val[A_EPT];     // (src<<15)|(tgt<<2)|t ; bucket = val>>17
    uint32_t rnk[A_EPT];
    #pragma unroll
    for (int k = 0; k < A_EPT / 4; ++k) {
        int4 s4 = sp[k];
        int4 t4 = tp[k];
        val[k*4+0] = ((uint32_t)s4.x << 15) | ((uint32_t)t4.x << 2) | t;
        val[k*4+1] = ((uint32_t)s4.y << 15) | ((uint32_t)t4.y << 2) | t;
        val[k*4+2] = ((uint32_t)s4.z << 15) | ((uint32_t)t4.z << 2) | t;
        val[k*4+3] = ((uint32_t)s4.w << 15) | ((uint32_t)t4.w << 2) | t;
    }
    #pragma unroll
    for (int k = 0; k < A_EPT; ++k)
        rnk[k] = atomicAdd(&hist[val[k] >> 17], 1u);
    __syncthreads();

    for (int i = tid; i < NB; i += 256) {
        uint32_t c = hist[i];
        cnt[(uint32_t)i * ABLK + blockIdx.x] = (uint8_t)(c > CAPBB ? CAPBB : c);
    }
    #pragma unroll
    for (int k = 0; k < A_EPT; ++k) {
        if (rnk[k] < CAPBB) {
            uint32_t b = val[k] >> 17;
            buf[((size_t)b * ABLK + blockIdx.x) * CAPBB + rnk[k]] = val[k] & 0x1FFFFu;
        }
    }
}

__global__ void __launch_bounds__(256) kB(const float* __restrict__ scores,
                                          const uint8_t* __restrict__ cnt,
                                          const uint32_t* __restrict__ buf,
                                          const float* __restrict__ f,
                                          float* __restrict__ out) {
    __shared__ uint32_t tab[RPB * SEG];      // 2 KB
    __shared__ uint8_t  cc[ABLK];            // 256 B
    int tid = threadIdx.x;
    for (int i = tid; i < RPB * SEG; i += 256) tab[i] = EMPTY;
    uint32_t b = blockIdx.x;
    cc[tid] = cnt[b * ABLK + tid];

    float st = f[0];
    float wsrc[HH], wtgt[HH], em[HH * TT];
    #pragma unroll
    for (int h = 0; h < HH; ++h) { wsrc[h] = f[1 + h]; wtgt[h] = f[5 + h]; }
    #pragma unroll
    for (int k = 0; k < HH * TT; ++k) em[k] = f[9 + k];
    __syncthreads();

    // dedup: 1 thread per sub-run (256 runs, mean 1 entry)
    const uint32_t* rb = buf + ((size_t)b * ABLK + tid) * CAPBB;
    int c = cc[tid];
    for (int i = 0; i < c; ++i) {
        uint32_t v   = rb[i];
        uint32_t row = (v >> 15) & 3u;
        uint32_t tgt = (v >> 2) & 8191u;
        uint32_t tt  = v & 3u;
        uint32_t inc = 1u << (13 + 4 * tt);
        uint32_t fresh = tgt | inc;
        uint32_t pos = (tgt * 2654435761u) >> 25;    // 7-bit probe start
        uint32_t base = row * SEG;
        while (true) {
            uint32_t cur = atomicCAS(&tab[base + pos], EMPTY, fresh);
            if (cur == EMPTY) break;
            bool done = false;
            while ((cur & 0x1FFFu) == tgt) {
                uint32_t prev = atomicCAS(&tab[base + pos], cur, cur + inc);
                if (prev == cur) { done = true; break; }
                cur = prev;
            }
            if (done) break;
            pos = (pos + 1) & (SEG - 1);
        }
    }
    __syncthreads();

    // accumulate: 4 waves x 1 row each, zero atomics
    int wave = tid >> 6, lane = tid & 63;
    int r = wave;
    float si = scores[b * RPB + r];
    float num[HH] = {0.f, 0.f, 0.f, 0.f};
    float den[HH] = {0.f, 0.f, 0.f, 0.f};
    #pragma unroll
    for (int half = 0; half < 2; ++half) {
        uint32_t w = tab[r * SEG + half * 64 + lane];
        if (w != EMPTY) {
            uint32_t tgt = w & 0x1FFFu;
            float c0 = (float)((w >> 13) & 15u);
            float c1 = (float)((w >> 17) & 15u);
            float c2 = (float)((w >> 21) & 15u);
            float c3 = (float)((w >> 25) & 15u);
            float ctot = c0 + c1 + c2 + c3;
            float sj = scores[tgt];
            #pragma unroll
            for (int h = 0; h < HH; ++h) {
                float a = ctot * (si * wsrc[h] + sj * wtgt[h])
                        + c0 * em[h * 4 + 0] + c1 * em[h * 4 + 1]
                        + c2 * em[h * 4 + 2] + c3 * em[h * 4 + 3];
                a = (a >= 0.f) ? a : NEG_SLOPE * a;
                float ex = __expf(a) - 1.f;
                den[h] += ex;
                num[h] += ex * sj;
            }
        }
    }
    #pragma unroll
    for (int m = 32; m > 0; m >>= 1) {
        #pragma unroll
        for (int h = 0; h < HH; ++h) {
            num[h] += __shfl_xor(num[h], m, 64);
            den[h] += __shfl_xor(den[h], m, 64);
        }
    }
    if (lane == 0) {
        float acc = 0.f;
        #pragma unroll
        for (int h = 0; h < HH; ++h)
            acc += (st + num[h]) / ((float)NN + den[h]);
        out[b * RPB + r] = acc * (1.f / HH);
    }
}

extern "C" void kernel_launch(void* const* d_in, const int* in_sizes, int n_in,
                              void* d_out, int out_size, void* d_ws, size_t ws_size,
                              hipStream_t stream) {
    const float* scores = (const float*)d_in[0];
    const float* ete    = (const float*)d_in[1];
    const int*   ei     = (const int*)d_in[2];
    const float* aw     = (const float*)d_in[3];
    float* out = (float*)d_out;

    uint8_t*  cnt = (uint8_t*)d_ws;
    float*    f   = (float*)((char*)d_ws + (size_t)NB * ABLK);
    uint32_t* buf = (uint32_t*)((char*)d_ws + (size_t)NB * ABLK + 1024);

    kA<<<ABLK + 1, 256, 0, stream>>>(ei, scores, ete, aw, cnt, buf, f);
    kB<<<NB, 256, 0, stream>>>(scores, cnt, buf, f, out);
}

// Round 6
// 95.820 us; speedup vs baseline: 1.0213x; 1.0213x over previous
//
#include <hip/hip_runtime.h>
#include <stdint.h>

// ScoreAggregation: N=8192, T=4 x E=131072 edges, H=4 heads.
// out_i = mean_h [ (S_total + sum_nz (e^leaky(A_ij)-1) s_j) / (N + sum_nz (e^leaky(A_ij)-1)) ]
// A_ij[h] = c_tot*(s_i*w_src[h] + s_j*w_tgt[h]) + sum_t cnt_t*emb[h][t]
// Dedup at (i,j) required (nonlinearity after aggregation).
// r5 lesson: sparse padded sub-runs cost ~70MB RFO traffic in kA. -> each kA
// block compacts its 2048 edges sorted-by-bucket in LDS, writes ONE dense
// 12KB region (u16 offs[2048] + u32 data[2048]) coalesced. Intermediate = 3MB
// (L2-resident), zero global atomics, zero capacity clamps.

#define NN 8192
#define TT 4
#define EE 131072
#define DD 32
#define HH 4
#define NEG_SLOPE 0.2f

#define NB   2048        // buckets = src>>2
#define RPB  4           // rows per bucket
#define SEG  128         // LDS hash slots per row (max distinct/row ~100)
#define ABLK 256         // kA blocks; each owns 2048 edges
#define EPB  2048        // edges per kA block
#define A_EPT 8          // edges per thread
#define REGB 12288       // region bytes: 4KB offs + 8KB data
#define EMPTY 0xFFFFFFFFu

// ws layout:
//   f       : float[32]            @ 0      (consts)
//   regions : ABLK x REGB          @ 256    (~3 MB)
// f: f[0]=S_total, f[1..4]=w_src, f[5..8]=w_tgt, f[9+h*4+t]=emb

__global__ void __launch_bounds__(256) kA(const int* __restrict__ ei,
                                          const float* __restrict__ scores,
                                          const float* __restrict__ ete,
                                          const float* __restrict__ aw,
                                          char* __restrict__ regs,
                                          float* __restrict__ f) {
    int tid = threadIdx.x;
    if (blockIdx.x == ABLK) {            // consts block
        __shared__ float red[256];
        float s = 0.f;
        for (int i = tid; i < NN; i += 256) s += scores[i];
        red[tid] = s;
        __syncthreads();
        for (int off = 128; off > 0; off >>= 1) {
            if (tid < off) red[tid] += red[tid + off];
            __syncthreads();
        }
        if (tid == 0) f[0] = red[0];
        if (tid < HH) {
            f[1 + tid] = aw[tid * (DD + 2)];            // w[0]
            f[5 + tid] = aw[tid * (DD + 2) + DD + 1];   // w[D+1]
        }
        if (tid < HH * TT) {
            int h = tid / TT, t = tid % TT;
            float acc = 0.f;
            for (int d = 0; d < DD; ++d)
                acc += ete[t * DD + d] * aw[h * (DD + 2) + 1 + d];
            f[9 + tid] = acc;
        }
        return;
    }

    __shared__ uint32_t hist[NB];        // 8 KB: counts, then reused as cursors
    __shared__ uint32_t offs[NB];        // 8 KB: exclusive bucket offsets
    __shared__ uint32_t stage[EPB];      // 8 KB: bucket-sorted packed entries
    __shared__ uint32_t wsum[256];       // thread-level partial sums

    #pragma unroll
    for (int j = 0; j < NB / 256; ++j) hist[tid + j * 256] = 0;
    __syncthreads();

    uint32_t gtid = blockIdx.x * 256u + (uint32_t)tid;   // [0, 65536)
    uint32_t t  = gtid >> 14;                            // 16384 threads/type
    uint32_t e0 = (gtid & 16383u) * A_EPT;
    const int4* sp = (const int4*)(ei + (size_t)(t * 2) * EE + e0);
    const int4* tp = (const int4*)(ei + (size_t)(t * 2 + 1) * EE + e0);

    uint32_t val[A_EPT];     // (src<<15)|(tgt<<2)|t ; bucket = val>>17
    uint32_t rnk[A_EPT];
    #pragma unroll
    for (int k = 0; k < A_EPT / 4; ++k) {
        int4 s4 = sp[k];
        int4 t4 = tp[k];
        val[k*4+0] = ((uint32_t)s4.x << 15) | ((uint32_t)t4.x << 2) | t;
        val[k*4+1] = ((uint32_t)s4.y << 15) | ((uint32_t)t4.y << 2) | t;
        val[k*4+2] = ((uint32_t)s4.z << 15) | ((uint32_t)t4.z << 2) | t;
        val[k*4+3] = ((uint32_t)s4.w << 15) | ((uint32_t)t4.w << 2) | t;
    }
    #pragma unroll
    for (int k = 0; k < A_EPT; ++k)
        rnk[k] = atomicAdd(&hist[val[k] >> 17], 1u);     // rank within bucket
    __syncthreads();

    // exclusive prefix scan over 2048 bucket counts (8 per thread)
    uint32_t loc[NB / 256];
    uint32_t lsum = 0;
    #pragma unroll
    for (int j = 0; j < NB / 256; ++j) {
        loc[j] = lsum;                                   // local exclusive
        lsum += hist[tid * (NB / 256) + j];
    }
    wsum[tid] = lsum;
    __syncthreads();
    for (int off = 1; off < 256; off <<= 1) {            // Hillis-Steele
        uint32_t u = (tid >= off) ? wsum[tid - off] : 0u;
        __syncthreads();
        wsum[tid] += u;
        __syncthreads();
    }
    uint32_t base = (tid == 0) ? 0u : wsum[tid - 1];
    #pragma unroll
    for (int j = 0; j < NB / 256; ++j)
        offs[tid * (NB / 256) + j] = base + loc[j];
    __syncthreads();

    #pragma unroll
    for (int k = 0; k < A_EPT; ++k)
        stage[offs[val[k] >> 17] + rnk[k]] = val[k] & 0x1FFFFu;
    __syncthreads();

    char* reg = regs + (size_t)blockIdx.x * REGB;
    uint16_t* h16 = (uint16_t*)reg;
    uint32_t* dat = (uint32_t*)(reg + 4096);
    #pragma unroll
    for (int j = 0; j < NB / 256; ++j)
        h16[tid * (NB / 256) + j] = (uint16_t)offs[tid * (NB / 256) + j];
    #pragma unroll
    for (int j = 0; j < EPB / 256; ++j)
        dat[j * 256 + tid] = stage[j * 256 + tid];
}

__global__ void __launch_bounds__(256) kB(const float* __restrict__ scores,
                                          const char* __restrict__ regs,
                                          const float* __restrict__ f,
                                          float* __restrict__ out) {
    __shared__ uint32_t tab[RPB * SEG];      // 2 KB
    int tid = threadIdx.x;
    tab[tid] = EMPTY;
    tab[tid + 256] = EMPTY;
    uint32_t b = blockIdx.x;

    float st = f[0];
    float wsrc[HH], wtgt[HH], em[HH * TT];
    #pragma unroll
    for (int h = 0; h < HH; ++h) { wsrc[h] = f[1 + h]; wtgt[h] = f[5 + h]; }
    #pragma unroll
    for (int k = 0; k < HH * TT; ++k) em[k] = f[9 + k];
    __syncthreads();

    // thread tid scans kA-block tid's run for bucket b (mean 1 entry)
    const char* reg = regs + (size_t)tid * REGB;
    const uint16_t* h16 = (const uint16_t*)reg;
    const uint32_t* dat = (const uint32_t*)(reg + 4096);
    uint32_t off = h16[b];
    uint32_t nxt = (b == NB - 1) ? (uint32_t)EPB : (uint32_t)h16[b + 1];
    for (uint32_t i = off; i < nxt; ++i) {
        uint32_t v   = dat[i];
        uint32_t row = (v >> 15) & 3u;
        uint32_t tgt = (v >> 2) & 8191u;
        uint32_t tt  = v & 3u;
        uint32_t inc = 1u << (13 + 4 * tt);
        uint32_t fresh = tgt | inc;
        uint32_t pos = (tgt * 2654435761u) >> 25;    // 7-bit probe start
        uint32_t hb = row * SEG;
        while (true) {
            uint32_t cur = atomicCAS(&tab[hb + pos], EMPTY, fresh);
            if (cur == EMPTY) break;
            bool done = false;
            while ((cur & 0x1FFFu) == tgt) {
                uint32_t prev = atomicCAS(&tab[hb + pos], cur, cur + inc);
                if (prev == cur) { done = true; break; }
                cur = prev;
            }
            if (done) break;
            pos = (pos + 1) & (SEG - 1);
        }
    }
    __syncthreads();

    // accumulate: 4 waves x 1 row each, zero atomics
    int wave = tid >> 6, lane = tid & 63;
    int r = wave;
    float si = scores[b * RPB + r];
    float num[HH] = {0.f, 0.f, 0.f, 0.f};
    float den[HH] = {0.f, 0.f, 0.f, 0.f};
    #pragma unroll
    for (int half = 0; half < 2; ++half) {
        uint32_t w = tab[r * SEG + half * 64 + lane];
        if (w != EMPTY) {
            uint32_t tgt = w & 0x1FFFu;
            float c0 = (float)((w >> 13) & 15u);
            float c1 = (float)((w >> 17) & 15u);
            float c2 = (float)((w >> 21) & 15u);
            float c3 = (float)((w >> 25) & 15u);
            float ctot = c0 + c1 + c2 + c3;
            float sj = scores[tgt];
            #pragma unroll
            for (int h = 0; h < HH; ++h) {
                float a = ctot * (si * wsrc[h] + sj * wtgt[h])
                        + c0 * em[h * 4 + 0] + c1 * em[h * 4 + 1]
                        + c2 * em[h * 4 + 2] + c3 * em[h * 4 + 3];
                a = (a >= 0.f) ? a : NEG_SLOPE * a;
                float ex = __expf(a) - 1.f;
                den[h] += ex;
                num[h] += ex * sj;
            }
        }
    }
    #pragma unroll
    for (int m = 32; m > 0; m >>= 1) {
        #pragma unroll
        for (int h = 0; h < HH; ++h) {
            num[h] += __shfl_xor(num[h], m, 64);
            den[h] += __shfl_xor(den[h], m, 64);
        }
    }
    if (lane == 0) {
        float acc = 0.f;
        #pragma unroll
        for (int h = 0; h < HH; ++h)
            acc += (st + num[h]) / ((float)NN + den[h]);
        out[b * RPB + r] = acc * (1.f / HH);
    }
}

extern "C" void kernel_launch(void* const* d_in, const int* in_sizes, int n_in,
                              void* d_out, int out_size, void* d_ws, size_t ws_size,
                              hipStream_t stream) {
    const float* scores = (const float*)d_in[0];
    const float* ete    = (const float*)d_in[1];
    const int*   ei     = (const int*)d_in[2];
    const float* aw     = (const float*)d_in[3];
    float* out = (float*)d_out;

    float* f    = (float*)d_ws;
    char*  regsp = (char*)d_ws + 256;

    kA<<<ABLK + 1, 256, 0, stream>>>(ei, scores, ete, aw, regsp, f);
    kB<<<NB, 256, 0, stream>>>(scores, regsp, f, out);
}